// Round 9
// baseline (702.869 us; speedup 1.0000x reference)
//
#include <hip/hip_runtime.h>
#include <stdint.h>
#include <math.h>

#define B_   32
#define S_   512
#define H_   256
#define M_   (B_*S_)     // 16384 tokens
#define KBIG 1024        // [hb|ha|hh|wv]
#define NB   1792        // 7*H
#define C_   5

typedef __bf16 bf16;
typedef __bf16 bf16x8 __attribute__((ext_vector_type(8)));
typedef float  floatx4 __attribute__((ext_vector_type(4)));

__device__ __forceinline__ float sigm(float x){ return 1.f/(1.f+expf(-x)); }

// async global->LDS, 16B per lane; LDS dest must be wave-uniform base + lane*16
__device__ __forceinline__ void gl16(const bf16* g, bf16* l){
    __builtin_amdgcn_global_load_lds(
        (const __attribute__((address_space(1))) unsigned int*)g,
        (__attribute__((address_space(3))) unsigned int*)l, 16, 0, 0);
}

// ---------- WT[n=g*256+h][k] = [W_lr[g,h,0:512] | W_c[g,h,:] | W_x[g,h,:]] (f32->bf16) ----------
__global__ void wcomb_k(const float* __restrict__ Wlr, const float* __restrict__ Wc,
                        const float* __restrict__ Wx, bf16* __restrict__ WT){
    int n = blockIdx.x;           // 0..1791
    int g = n >> 8, h = n & 255;
    int k4 = threadIdx.x * 4;     // 0..1020
    const float* src;
    if (k4 < 512)      src = Wlr + ((size_t)(g*256 + h))*512 + k4;
    else if (k4 < 768) src = Wc  + ((size_t)(g*256 + h))*256 + (k4 - 512);
    else               src = Wx  + ((size_t)(g*256 + h))*256 + (k4 - 768);
    float4 v = *(const float4*)src;
    bf16 o[4] = {(bf16)v.x,(bf16)v.y,(bf16)v.z,(bf16)v.w};
    *(uint2*)&WT[(size_t)n*KBIG + k4] = *(uint2*)o;
}

// ---------- generic f32 -> bf16 (n multiple of 1024) ----------
__global__ void cvtw_k(const float* __restrict__ a, bf16* __restrict__ o){
    int i4 = (blockIdx.x*256 + threadIdx.x)*4;
    float4 v = *(const float4*)(a + i4);
    bf16 t[4] = {(bf16)v.x,(bf16)v.y,(bf16)v.z,(bf16)v.w};
    *(uint2*)(o + i4) = *(uint2*)t;
}

// ---------- wv[m,h] = (bf16)embed[idx[m],h] ----------
__global__ void gather_k(const int* __restrict__ idx, const float* __restrict__ embed,
                         bf16* __restrict__ wv){
    int i4 = (blockIdx.x*256 + threadIdx.x)*4;
    int m = i4 >> 8, h = i4 & 255;
    float4 v = *(const float4*)(embed + (size_t)idx[m]*H_ + h);
    bf16 o[4] = {(bf16)v.x,(bf16)v.y,(bf16)v.z,(bf16)v.w};
    *(uint2*)(wv + (size_t)m*H_ + h) = *(uint2*)o;
}

// ---------- two-stage mean over S ----------
__global__ void mean1_k(const float* __restrict__ x, float* __restrict__ part){
    int b = blockIdx.x, c = blockIdx.y, h = threadIdx.x;   // grid (B_,16)
    const float* p = x + ((size_t)b*S_ + c*32)*H_ + h;
    float s = 0.f;
    #pragma unroll 8
    for (int t=0;t<32;t++) s += p[(size_t)t*H_];
    part[((size_t)b*16 + c)*H_ + h] = s;
}
__global__ void mean2_k(const float* __restrict__ part, float* __restrict__ out){
    int b = blockIdx.x, h = threadIdx.x;
    float s = 0.f;
    #pragma unroll
    for (int c=0;c<16;c++) s += part[((size_t)b*16 + c)*H_ + h];
    out[b*H_ + h] = s * (1.f/512.f);
}

// ---------- X[m] = [hb | ha | hh | wv] (bf16), wave per row, vectorized ----------
__global__ void buildx_k(const float* __restrict__ hh, const bf16* __restrict__ wv,
                         bf16* __restrict__ X){
    int tid = threadIdx.x, wave = tid >> 6, lane = tid & 63;
    int m = blockIdx.x*4 + wave;                    // grid M_/4
    int s = m & (S_-1);
    int h0 = lane*4;
    const float* hr = hh + (size_t)m*H_ + h0;
    float hb[4] = {0,0,0,0}, ha[4] = {0,0,0,0};
    if (s>=1){    float4 a = *(const float4*)(hr - H_);   hb[0]+=a.x; hb[1]+=a.y; hb[2]+=a.z; hb[3]+=a.w; }
    if (s>=2){    float4 a = *(const float4*)(hr - 2*H_); hb[0]+=a.x; hb[1]+=a.y; hb[2]+=a.z; hb[3]+=a.w; }
    if (s<=S_-2){ float4 a = *(const float4*)(hr + H_);   ha[0]+=a.x; ha[1]+=a.y; ha[2]+=a.z; ha[3]+=a.w; }
    if (s<=S_-3){ float4 a = *(const float4*)(hr + 2*H_); ha[0]+=a.x; ha[1]+=a.y; ha[2]+=a.z; ha[3]+=a.w; }
    float4 hc = *(const float4*)hr;
    uint2 wvv = *(const uint2*)(wv + (size_t)m*H_ + h0);
    bf16* xr = X + (size_t)m*KBIG;
    bf16 o[4];
    o[0]=(bf16)hb[0]; o[1]=(bf16)hb[1]; o[2]=(bf16)hb[2]; o[3]=(bf16)hb[3];
    *(uint2*)(xr + h0) = *(uint2*)o;
    o[0]=(bf16)ha[0]; o[1]=(bf16)ha[1]; o[2]=(bf16)ha[2]; o[3]=(bf16)ha[3];
    *(uint2*)(xr + 256 + h0) = *(uint2*)o;
    o[0]=(bf16)hc.x;  o[1]=(bf16)hc.y;  o[2]=(bf16)hc.z;  o[3]=(bf16)hc.w;
    *(uint2*)(xr + 512 + h0) = *(uint2*)o;
    *(uint2*)(xr + 768 + h0) = wvv;
}

// ---------- 5 small matvecs: res[b*5+j][h] ----------
__global__ void mv5_k(const float* __restrict__ sv, const float* __restrict__ avg,
    const float* __restrict__ Wfg_g, const float* __restrict__ Wfg_h,
    const float* __restrict__ Wog_g, const float* __restrict__ Wog_h,
    const float* __restrict__ Wfgi_g, float* __restrict__ res){
    int j = blockIdx.x, b = blockIdx.y, h = threadIdx.x;   // grid (5,B_)
    const float* vec = (j==1 || j==3) ? avg + b*H_ : sv + b*H_;
    const float* W   = (j==0)?Wfg_g:(j==1)?Wfg_h:(j==2)?Wog_g:(j==3)?Wog_h:Wfgi_g;
    __shared__ float v[H_];
    v[h] = vec[h]; __syncthreads();
    const float* w = W + (size_t)h*H_;
    float d = 0.f;
    for (int k=0;k<H_;k++) d += v[k]*w[k];
    res[((size_t)b*5 + j)*H_ + h] = d;
}
__global__ void comb_k(const float* __restrict__ res, const float* __restrict__ b_fg,
                       const float* __restrict__ gbias, const float* __restrict__ b_fgi,
                       float* __restrict__ fhg, float* __restrict__ ogg,
                       float* __restrict__ svg){
    int b = blockIdx.x, h = threadIdx.x;
    const float* r = res + (size_t)b*5*H_;
    fhg[b*H_+h] = sigm(r[h] + r[H_+h] + b_fg[h]);
    ogg[b*H_+h] = sigm(r[2*H_+h] + r[3*H_+h] + gbias[5*H_+h]);  // gate_bias[5] per ref
    svg[b*H_+h] = r[4*H_+h] + b_fgi[h];
}

// ---------- MFMA GEMM: 128 rows x 256 cols per block (2 N-tiles share A) ----------
template<int EPI>
__global__ __launch_bounds__(256)
void mgemm_k(const bf16* __restrict__ A, const bf16* __restrict__ BT,
             bf16* __restrict__ C, const float* __restrict__ gt,
             int Kdim, int lda, int ldb, int ldc){
    __shared__ alignas(16) bf16 lsA [128*32];
    __shared__ alignas(16) bf16 lsB0[128*32];
    __shared__ alignas(16) bf16 lsB1[128*32];
    int tid  = threadIdx.x;
    int m0 = blockIdx.y * 128, n0 = blockIdx.x * 256;
    int wave = tid >> 6, lane = tid & 63;
    int wm = (wave & 1) * 64, wn = (wave >> 1) * 64;
    int lrow = lane & 15, quad = lane >> 4;

    floatx4 zero = {0.f,0.f,0.f,0.f};
    floatx4 acc[2][4][4];
    #pragma unroll
    for (int t=0;t<2;t++)
        #pragma unroll
        for (int i=0;i<4;i++)
            #pragma unroll
            for (int j=0;j<4;j++) acc[t][i][j] = zero;

    int srow = tid >> 2;            // 0..63
    int scol = (tid & 3) * 8;       // lds offset = tid*16B (HW contract)
    const bf16* Abase  = A  + (size_t)(m0 + srow)*lda + scol;
    const bf16* B0base = BT + (size_t)(n0 + srow)*ldb + scol;
    const bf16* B1base = BT + (size_t)(n0 + 128 + srow)*ldb + scol;
    bf16* dA0 = &lsA [srow*32 + scol];
    bf16* dA1 = &lsA [(64+srow)*32 + scol];
    bf16* dB00= &lsB0[srow*32 + scol];
    bf16* dB01= &lsB0[(64+srow)*32 + scol];
    bf16* dB10= &lsB1[srow*32 + scol];
    bf16* dB11= &lsB1[(64+srow)*32 + scol];

    for (int k0 = 0; k0 < Kdim; k0 += 32){
        __syncthreads();
        gl16(Abase  + k0,                  dA0);
        gl16(Abase  + (size_t)64*lda + k0, dA1);
        gl16(B0base + k0,                  dB00);
        gl16(B0base + (size_t)64*ldb + k0, dB01);
        gl16(B1base + k0,                  dB10);
        gl16(B1base + (size_t)64*ldb + k0, dB11);
        __syncthreads();
        bf16x8 af[4], b0[4], b1[4];
        #pragma unroll
        for (int mi=0;mi<4;mi++) af[mi] = *(const bf16x8*)&lsA [(wm+mi*16+lrow)*32 + quad*8];
        #pragma unroll
        for (int ni=0;ni<4;ni++) b0[ni] = *(const bf16x8*)&lsB0[(wn+ni*16+lrow)*32 + quad*8];
        #pragma unroll
        for (int ni=0;ni<4;ni++) b1[ni] = *(const bf16x8*)&lsB1[(wn+ni*16+lrow)*32 + quad*8];
        #pragma unroll
        for (int mi=0;mi<4;mi++)
            #pragma unroll
            for (int ni=0;ni<4;ni++){
                acc[0][mi][ni] = __builtin_amdgcn_mfma_f32_16x16x32_bf16(af[mi], b0[ni], acc[0][mi][ni], 0, 0, 0);
                acc[1][mi][ni] = __builtin_amdgcn_mfma_f32_16x16x32_bf16(af[mi], b1[ni], acc[1][mi][ni], 0, 0, 0);
            }
    }

    #pragma unroll
    for (int t=0;t<2;t++)
        #pragma unroll
        for (int mi=0;mi<4;mi++)
            #pragma unroll
            for (int ni=0;ni<4;ni++){
                int row = m0 + wm + mi*16 + quad*4;     // C/D: row = quad*4 + r
                int col = n0 + t*128 + wn + ni*16 + lrow;
                #pragma unroll
                for (int r=0;r<4;r++){
                    float v = acc[t][mi][ni][r];
                    if (EPI) v += gt[(size_t)((row+r)>>9)*NB + col];
                    C[(size_t)(row+r)*ldc + col] = (bf16)v;
                }
            }
}

// ---------- fused score+partial: wave per token, h = lane*4+j, vectorized ----------
__global__ void scorep_k(const bf16* __restrict__ fgih, const float* __restrict__ svg,
                         const float* __restrict__ cs, float* __restrict__ part){
    int chunk = blockIdx.x, b = blockIdx.y;                 // grid (32,B_)
    int tid = threadIdx.x, wave = tid >> 6, lane = tid & 63;
    __shared__ float acc4[4][256];
    int h0 = lane*4;
    float4 sw = *(const float4*)(svg + b*H_ + h0);
    float swa[4] = {sw.x, sw.y, sw.z, sw.w};
    float acc[4] = {0.f,0.f,0.f,0.f};
    for (int t=wave; t<16; t+=4){
        int m = b*S_ + chunk*16 + t;
        bf16 fv[4]; *(uint2*)fv = *(const uint2*)(fgih + (size_t)m*H_ + h0);
        float e[4], loc = 0.f;
        #pragma unroll
        for (int j=0;j<4;j++){ e[j] = expf(sigm(swa[j] + (float)fv[j])); loc += e[j]; }
        #pragma unroll
        for (int off=32; off; off>>=1) loc += __shfl_xor(loc, off, 64);
        float inv = 1.f/loc;
        float4 cr = *(const float4*)(cs + (size_t)m*H_ + h0);
        acc[0] += e[0]*inv*cr.x; acc[1] += e[1]*inv*cr.y;
        acc[2] += e[2]*inv*cr.z; acc[3] += e[3]*inv*cr.w;
    }
    *(float4*)&acc4[wave][h0] = *(float4*)acc;
    __syncthreads();
    part[((size_t)b*32 + chunk)*H_ + tid] =
        acc4[0][tid] + acc4[1][tid] + acc4[2][tid] + acc4[3][tid];
}

// ---------- new_scs / new_sv (sums 32 partials) ----------
__global__ void newscs_k(const float* __restrict__ part, const float* __restrict__ fhg,
                         const float* __restrict__ ogg, const float* __restrict__ scs_in,
                         float* __restrict__ scs_out, float* __restrict__ sv_out){
    int b = blockIdx.x, h = threadIdx.x;
    __shared__ float r[256];
    float dot = 0.f;
    #pragma unroll 8
    for (int c=0;c<32;c++) dot += part[((size_t)b*32+c)*H_ + h];
    float e = expf(fhg[b*H_+h]);
    r[h] = e; __syncthreads();
    for (int off=128; off; off>>=1){ if (h<off) r[h] += r[h+off]; __syncthreads(); }
    float ns = (e / r[0]) * scs_in[b*H_+h] + dot;
    scs_out[b*H_+h] = ns;
    sv_out[b*H_+h]  = ogg[b*H_+h] * tanhf(ns);
}

// ---------- gt[b, g*256+h] = sum_k new_sv[b,k]*W_g[g,h,k] + gate_bias[g,h] ----------
__global__ void gterm_k(const float* __restrict__ svn, const float* __restrict__ Wg,
                        const float* __restrict__ gbias, float* __restrict__ gt){
    int g = blockIdx.x, b = blockIdx.y, h = threadIdx.x;
    __shared__ float s[H_];
    s[h] = svn[b*H_+h]; __syncthreads();
    const float* w = Wg + ((size_t)g*H_ + h)*H_;
    float d = 0.f;
    for (int k=0;k<H_;k++) d += s[k]*w[k];
    gt[(size_t)b*NB + g*H_ + h] = d + gbias[g*H_+h];
}

// ---------- joint softmax over 5H + state update: wave/token, h = lane*4+j ----------
__global__ void gates_k(const bf16* __restrict__ pre, const float* __restrict__ cs_in,
                        const float* __restrict__ scs_in,
                        float* __restrict__ hh_out, float* __restrict__ cs_out){
    int tid = threadIdx.x, wave = tid >> 6, lane = tid & 63;
    int m = blockIdx.x*4 + wave;                             // grid M_/4
    int b = m >> 9, s = m & (S_-1);
    int h0 = lane*4;
    const bf16* row = pre + (size_t)m*NB + h0;
    float ex[5][4], og[4], u[4];
    float loc = 0.f;
    #pragma unroll
    for (int g=0; g<5; ++g){
        bf16 v[4]; *(uint2*)v = *(const uint2*)(row + g*H_);
        #pragma unroll
        for (int j=0;j<4;j++){ float e = expf(sigm((float)v[j])); ex[g][j] = e; loc += e; }
    }
    { bf16 v[4]; *(uint2*)v = *(const uint2*)(row + 5*H_);
      #pragma unroll
      for (int j=0;j<4;j++) og[j] = sigm((float)v[j]); }
    { bf16 v[4]; *(uint2*)v = *(const uint2*)(row + 6*H_);
      #pragma unroll
      for (int j=0;j<4;j++) u[j]  = tanhf((float)v[j]); }
    #pragma unroll
    for (int off=32; off; off>>=1) loc += __shfl_xor(loc, off, 64);
    float inv = 1.f / loc;
    size_t i = (size_t)m*H_ + h0;
    float4 cm = *(const float4*)(cs_in + i);
    float cb[4] = {0,0,0,0}, ca[4] = {0,0,0,0};
    if (s>=1){    float4 a = *(const float4*)(cs_in + i - H_);   cb[0]+=a.x; cb[1]+=a.y; cb[2]+=a.z; cb[3]+=a.w; }
    if (s>=2){    float4 a = *(const float4*)(cs_in + i - 2*H_); cb[0]+=a.x; cb[1]+=a.y; cb[2]+=a.z; cb[3]+=a.w; }
    if (s<=S_-2){ float4 a = *(const float4*)(cs_in + i + H_);   ca[0]+=a.x; ca[1]+=a.y; ca[2]+=a.z; ca[3]+=a.w; }
    if (s<=S_-3){ float4 a = *(const float4*)(cs_in + i + 2*H_); ca[0]+=a.x; ca[1]+=a.y; ca[2]+=a.z; ca[3]+=a.w; }
    float4 sc = *(const float4*)(scs_in + b*H_ + h0);
    float scv[4] = {sc.x, sc.y, sc.z, sc.w};
    float cmv[4] = {cm.x, cm.y, cm.z, cm.w};
    float ncs[4], nhh[4];
    #pragma unroll
    for (int j=0;j<4;j++){
        // gate order i,l,r,f,s: new_cs = l*cb + f*cs + r*ca + s*scs + i*u
        float nc = ex[1][j]*inv*cb[j] + ex[3][j]*inv*cmv[j] + ex[2][j]*inv*ca[j]
                 + ex[4][j]*inv*scv[j] + ex[0][j]*inv*u[j];
        ncs[j] = nc;
        nhh[j] = og[j] * tanhf(nc);
    }
    *(float4*)(cs_out + i) = *(float4*)ncs;
    *(float4*)(hh_out + i) = *(float4*)nhh;
}

// ---------- output head (float32 out) ----------
__global__ void head_k(const float* __restrict__ avgh, const float* __restrict__ sv,
                       const float* __restrict__ W1, const float* __restrict__ b1,
                       const float* __restrict__ Wout, const float* __restrict__ bout,
                       float* __restrict__ out){
    int b = blockIdx.x, t = threadIdx.x;
    __shared__ float conc[H_];
    __shared__ float fc[8];
    const float* wr = W1 + (size_t)t*512;
    float d = b1[t];
    for (int k=0;k<H_;k++) d += avgh[b*H_+k]*wr[k];
    for (int k=0;k<H_;k++) d += sv[b*H_+k]*wr[256+k];
    conc[t] = d;
    __syncthreads();
    if (t < C_){
        const float* wo = Wout + (size_t)t*H_;
        float s = bout[t];
        for (int i=0;i<H_;i++) s += conc[i]*wo[i];
        fc[t] = s;
    }
    __syncthreads();
    if (t == 0){
        float mx = fc[0];
        for (int c=1;c<C_;c++) mx = fmaxf(mx, fc[c]);
        float se = 0.f;
        for (int c=0;c<C_;c++) se += expf(fc[c]-mx);
        float lse = mx + logf(se);
        for (int c=0;c<C_;c++) out[b*C_+c] = fc[c]-lse;
    }
    out[B_*C_ + b*H_ + t] = sv[b*H_+t];
}

// ---------------- host ----------------
extern "C" void kernel_launch(void* const* d_in, const int* in_sizes, int n_in,
                              void* d_out, int out_size, void* d_ws, size_t ws_size,
                              hipStream_t stream){
    const int*   idx    = (const int*)d_in[0];
    const float* hh0    = (const float*)d_in[2];
    const float* cs0    = (const float*)d_in[3];
    const float* embed  = (const float*)d_in[4];
    const float* Wlr    = (const float*)d_in[5];
    const float* Wc     = (const float*)d_in[6];
    const float* Wx     = (const float*)d_in[7];
    const float* Wg     = (const float*)d_in[8];
    const float* gbias  = (const float*)d_in[9];
    const float* Wfg_g  = (const float*)d_in[10];
    const float* Wfg_h  = (const float*)d_in[11];
    const float* Wfgi_g = (const float*)d_in[12];
    const float* Wfgi_h = (const float*)d_in[13];
    const float* Wog_g  = (const float*)d_in[14];
    const float* Wog_h  = (const float*)d_in[15];
    const float* b_fg   = (const float*)d_in[16];
    const float* b_fgi  = (const float*)d_in[17];
    const float* W1     = (const float*)d_in[18];
    const float* b1     = (const float*)d_in[19];
    const float* Wout   = (const float*)d_in[20];
    const float* bout   = (const float*)d_in[21];

    uint8_t* p = (uint8_t*)d_ws;
    auto alloc = [&](size_t bytes)->void*{ void* r=(void*)p; p += (bytes + 255) & ~(size_t)255; return r; };
    bf16*  WT    = (bf16*)alloc((size_t)NB*KBIG*2);    //  3.7 MB
    bf16*  WfgiT = (bf16*)alloc((size_t)H_*H_*2);
    bf16*  X     = (bf16*)alloc((size_t)M_*KBIG*2);    // 33.6 MB
    bf16*  wv    = (bf16*)alloc((size_t)M_*H_*2);      //  8.4 MB
    bf16*  pre   = (bf16*)alloc((size_t)M_*NB*2);      // 58.7 MB
    bf16*  fgih  = (bf16*)alloc((size_t)M_*H_*2);      //  8.4 MB
    float* hhA = (float*)alloc((size_t)M_*H_*4);
    float* csA = (float*)alloc((size_t)M_*H_*4);
    float* hhB = (float*)alloc((size_t)M_*H_*4);
    float* csB = (float*)alloc((size_t)M_*H_*4);
    float* mpart= (float*)alloc((size_t)B_*16*H_*4);
    float* part = (float*)alloc((size_t)B_*32*H_*4);
    float* res5 = (float*)alloc((size_t)B_*5*H_*4);
    float* avgh = (float*)alloc(B_*H_*4);
    float* fhg  = (float*)alloc(B_*H_*4);
    float* ogg  = (float*)alloc(B_*H_*4);
    float* svg  = (float*)alloc(B_*H_*4);
    float* svP0 = (float*)alloc(B_*H_*4);
    float* svP1 = (float*)alloc(B_*H_*4);
    float* scP0 = (float*)alloc(B_*H_*4);
    float* scP1 = (float*)alloc(B_*H_*4);
    float* gt   = (float*)alloc((size_t)B_*NB*4);

    wcomb_k <<<NB,          256, 0, stream>>>(Wlr, Wc, Wx, WT);
    cvtw_k  <<<(H_*H_)/1024,256, 0, stream>>>(Wfgi_h, WfgiT);
    gather_k<<<(M_*H_)/1024,256, 0, stream>>>(idx, embed, wv);
    mean1_k <<<dim3(B_,16), 256, 0, stream>>>(hh0, mpart);
    mean2_k <<<B_,          256, 0, stream>>>(mpart, svP0);   // sv0 == avg_hh(layer0)
    mean1_k <<<dim3(B_,16), 256, 0, stream>>>(cs0, mpart);
    mean2_k <<<B_,          256, 0, stream>>>(mpart, scP0);

    const float *hin = hh0, *cin = cs0;
    float *hout = hhA, *cout = csA;
    float *svin = svP0, *scin = scP0, *svout = svP1, *scout = scP1;

    for (int l=0; l<2; ++l){
        const float* avgp;
        if (l == 0){
            avgp = svin;            // mean(hh0) == initial sv
        } else {
            mean1_k<<<dim3(B_,16), 256, 0, stream>>>(hin, mpart);
            mean2_k<<<B_,          256, 0, stream>>>(mpart, avgh);
            avgp = avgh;
        }
        mv5_k   <<<dim3(5,B_), 256, 0, stream>>>(svin, avgp, Wfg_g, Wfg_h, Wog_g,
                                                 Wog_h, Wfgi_g, res5);
        comb_k  <<<B_, 256, 0, stream>>>(res5, b_fg, gbias, b_fgi, fhg, ogg, svg);
        buildx_k<<<M_/4, 256, 0, stream>>>(hin, wv, X);
        mgemm_k<0><<<dim3(1,128), 256, 0, stream>>>(X+512, WfgiT, fgih, nullptr,
                                                    H_, KBIG, H_, H_);
        scorep_k<<<dim3(32,B_), 256, 0, stream>>>(fgih, svg, cin, part);
        newscs_k<<<B_, 256, 0, stream>>>(part, fhg, ogg, scin, scout, svout);
        gterm_k <<<dim3(7,B_), 256, 0, stream>>>(svout, Wg, gbias, gt);
        mgemm_k<1><<<dim3(7,128), 256, 0, stream>>>(X, WT, pre, gt,
                                                    KBIG, KBIG, KBIG, NB);
        gates_k <<<M_/4, 256, 0, stream>>>(pre, cin, scin, hout, cout);
        hin = hout; cin = cout;
        hout = (l==0) ? hhB : hhA;
        cout = (l==0) ? csB : csA;
        float* q;
        q = svin; svin = svout; svout = q;
        q = scin; scin = scout; scout = q;
    }
    mean1_k<<<dim3(B_,16), 256, 0, stream>>>(hin, mpart);
    mean2_k<<<B_,          256, 0, stream>>>(mpart, avgh);
    head_k <<<B_, 256, 0, stream>>>(avgh, svin, W1, b1, Wout, bout, (float*)d_out);
}